// Round 2
// baseline (70.027 us; speedup 1.0000x reference)
//
#include <hip/hip_runtime.h>

#define NQ 12
#define NSTATE 4096
#define NL 5
#define TPB 256

// LDS slot swizzle: XOR bits 4..7 into bits 0..3 -> all three gate passes hit
// the ds_read_b64 bank floor (4 lanes/bank-pair, distinct addrs).
__device__ __forceinline__ int swz(int i) { return i ^ ((i >> 4) & 15); }

// Composition of the full CNOT ring CNOT(q,(q+1)%12), q=0..11 (qubit q = bit 11-q):
// new_state[i] = old_state[f(i)],  f(i) = i ^ (i>>1) ^ (bit0(i) ? 0xC00 : 0).
__device__ __forceinline__ int permf(int i) {
    return i ^ (i >> 1) ^ ((-(i & 1)) & 0xC00);
}

// Apply a single-qubit gate on nibble-bit K of the 16 in-register amplitudes.
template <int K>
__device__ __forceinline__ void apply_gate(float2 (&v)[16], const float2* __restrict__ Uq) {
    const float2 u00 = Uq[0], u01 = Uq[1], u10 = Uq[2], u11 = Uq[3];
#pragma unroll
    for (int h = 0; h < 8; ++h) {
        const int m0 = ((h >> K) << (K + 1)) | (h & ((1 << K) - 1));
        const int m1 = m0 | (1 << K);
        const float2 a = v[m0], c = v[m1];
        float2 n0, n1;
        n0.x = fmaf(u00.x, a.x, fmaf(-u00.y, a.y, fmaf(u01.x, c.x, -u01.y * c.y)));
        n0.y = fmaf(u00.x, a.y, fmaf( u00.y, a.x, fmaf(u01.x, c.y,  u01.y * c.x)));
        n1.x = fmaf(u10.x, a.x, fmaf(-u10.y, a.y, fmaf(u11.x, c.x, -u11.y * c.y)));
        n1.y = fmaf(u10.x, a.y, fmaf( u10.y, a.x, fmaf(u11.x, c.y,  u11.y * c.x)));
        v[m0] = n0;
        v[m1] = n1;
    }
}

extern "C" __global__ void __launch_bounds__(TPB)
qnet_kernel(const float* __restrict__ x, const float* __restrict__ iw,
            const float* __restrict__ th, const float* __restrict__ ow,
            float* __restrict__ out) {
    __shared__ float2 st[2][NSTATE];     // 2 x 32 KB state (swizzled slots)
    __shared__ float2 U[2][NL][NQ][4];   // per-element gate matrices
    __shared__ float wz[2][4][4];        // per-wave partial Z sums

    const int b0 = blockIdx.x * 2;
    const int tid = threadIdx.x;

    // --- init both states |0...0> ---
#pragma unroll
    for (int r = 0; r < 16; ++r) {
        st[0][tid * 16 + r] = make_float2(0.f, 0.f);
        st[1][tid * 16 + r] = make_float2(0.f, 0.f);
    }
    if (tid == 0) { st[0][0] = make_float2(1.f, 0.f); st[1][0] = make_float2(1.f, 0.f); }

    // --- precompute all 120 gate matrices U = M(b,c) @ Rx(a) ---
    if (tid < 2 * NL * NQ) {
        const int e = tid / (NL * NQ);
        const int idx = tid % (NL * NQ);
        const int l = idx / NQ, q = idx % NQ;
        const float xv = tanhf(x[(b0 + e) * NQ + q]);
        const float a = iw[l * NQ + q] * xv;
        const float bt = th[(l * NQ + q) * 2 + 0];
        const float ct = th[(l * NQ + q) * 2 + 1];
        float sa, ca; sincosf(0.5f * a, &sa, &ca);
        float sb, cb; sincosf(0.5f * bt, &sb, &cb);
        float sc, cc; sincosf(0.5f * ct, &sc, &cc);
        const float M00r = cc * cb, M00i = -sc * cb;
        const float M01r = -cc * sb, M01i = sc * sb;
        const float M10r = cc * sb, M10i = sc * sb;
        const float M11r = cc * cb, M11i = sc * cb;
        U[e][l][q][0] = make_float2(fmaf(M00r, ca,  sa * M01i), fmaf(M00i, ca, -sa * M01r));
        U[e][l][q][1] = make_float2(fmaf(ca, M01r,  sa * M00i), fmaf(ca, M01i, -sa * M00r));
        U[e][l][q][2] = make_float2(fmaf(M10r, ca,  sa * M11i), fmaf(M10i, ca, -sa * M11r));
        U[e][l][q][3] = make_float2(fmaf(ca, M11r,  sa * M10i), fmaf(ca, M11i, -sa * M10r));
    }
    __syncthreads();

    for (int l = 0; l < NL; ++l) {
        float2 va[16], vb[16];

        // --- pass A: bits 0..3 (qubits 11..8); gather fuses previous layer's CNOT perm ---
#pragma unroll
        for (int r = 0; r < 16; ++r) {
            const int i = tid * 16 + r;
            const int j = (l == 0) ? i : permf(i);
            va[r] = st[0][swz(j)];
            vb[r] = st[1][swz(j)];
        }
        if (l > 0) __syncthreads();  // all reads drained (lgkmcnt(0)) before overwrite
        apply_gate<0>(va, U[0][l][11]);
        apply_gate<1>(va, U[0][l][10]);
        apply_gate<2>(va, U[0][l][9]);
        apply_gate<3>(va, U[0][l][8]);
        apply_gate<0>(vb, U[1][l][11]);
        apply_gate<1>(vb, U[1][l][10]);
        apply_gate<2>(vb, U[1][l][9]);
        apply_gate<3>(vb, U[1][l][8]);
#pragma unroll
        for (int r = 0; r < 16; ++r) {
            st[0][swz(tid * 16 + r)] = va[r];
            st[1][swz(tid * 16 + r)] = vb[r];
        }
        __syncthreads();

        // --- pass B: bits 4..7 (qubits 7..4) ---
        {
            const int base = ((tid >> 4) << 8) | (tid & 15);
#pragma unroll
            for (int m = 0; m < 16; ++m) {
                va[m] = st[0][swz(base | (m << 4))];
                vb[m] = st[1][swz(base | (m << 4))];
            }
            apply_gate<0>(va, U[0][l][7]);
            apply_gate<1>(va, U[0][l][6]);
            apply_gate<2>(va, U[0][l][5]);
            apply_gate<3>(va, U[0][l][4]);
            apply_gate<0>(vb, U[1][l][7]);
            apply_gate<1>(vb, U[1][l][6]);
            apply_gate<2>(vb, U[1][l][5]);
            apply_gate<3>(vb, U[1][l][4]);
#pragma unroll
            for (int m = 0; m < 16; ++m) {
                st[0][swz(base | (m << 4))] = va[m];
                st[1][swz(base | (m << 4))] = vb[m];
            }
        }
        __syncthreads();

        // --- pass C: bits 8..11 (qubits 3..0) ---
        {
#pragma unroll
            for (int m = 0; m < 16; ++m) {
                va[m] = st[0][swz((m << 8) | tid)];
                vb[m] = st[1][swz((m << 8) | tid)];
            }
            apply_gate<0>(va, U[0][l][3]);
            apply_gate<1>(va, U[0][l][2]);
            apply_gate<2>(va, U[0][l][1]);
            apply_gate<3>(va, U[0][l][0]);
            apply_gate<0>(vb, U[1][l][3]);
            apply_gate<1>(vb, U[1][l][2]);
            apply_gate<2>(vb, U[1][l][1]);
            apply_gate<3>(vb, U[1][l][0]);
#pragma unroll
            for (int m = 0; m < 16; ++m) {
                st[0][swz((m << 8) | tid)] = va[m];
                st[1][swz((m << 8) | tid)] = vb[m];
            }
        }
        __syncthreads();
    }

    // --- final CNOT perm fused into measurement ---
    float psa = 0.f, psb = 0.f;
#pragma unroll
    for (int r = 0; r < 16; ++r) {
        const int i = tid * 16 + r;
        const int j = swz(permf(i));
        const float2 a = st[0][j];
        const float2 c = st[1][j];
        psa = fmaf(a.x, a.x, fmaf(a.y, a.y, psa));
        psb = fmaf(c.x, c.x, fmaf(c.y, c.y, psb));
    }
    // Z on qubits 0..3 = bits 11..8 of i = bits 7..4 of tid (constant per thread)
    float s0a = (tid & 128) ? -psa : psa, s0b = (tid & 128) ? -psb : psb;
    float s1a = (tid & 64) ? -psa : psa,  s1b = (tid & 64) ? -psb : psb;
    float s2a = (tid & 32) ? -psa : psa,  s2b = (tid & 32) ? -psb : psb;
    float s3a = (tid & 16) ? -psa : psa,  s3b = (tid & 16) ? -psb : psb;
#pragma unroll
    for (int off = 32; off > 0; off >>= 1) {
        s0a += __shfl_xor(s0a, off); s0b += __shfl_xor(s0b, off);
        s1a += __shfl_xor(s1a, off); s1b += __shfl_xor(s1b, off);
        s2a += __shfl_xor(s2a, off); s2b += __shfl_xor(s2b, off);
        s3a += __shfl_xor(s3a, off); s3b += __shfl_xor(s3b, off);
    }
    const int wave = tid >> 6;
    if ((tid & 63) == 0) {
        wz[0][wave][0] = s0a; wz[0][wave][1] = s1a; wz[0][wave][2] = s2a; wz[0][wave][3] = s3a;
        wz[1][wave][0] = s0b; wz[1][wave][1] = s1b; wz[1][wave][2] = s2b; wz[1][wave][3] = s3b;
    }
    __syncthreads();
    if (tid < 8) {
        const int e = tid >> 2, k = tid & 3;
        const float z = wz[e][0][k] + wz[e][1][k] + wz[e][2][k] + wz[e][3][k];
        out[(b0 + e) * 4 + k] = ow[k] * z;
    }
}

extern "C" void kernel_launch(void* const* d_in, const int* in_sizes, int n_in,
                              void* d_out, int out_size, void* d_ws, size_t ws_size,
                              hipStream_t stream) {
    const float* x  = (const float*)d_in[0];
    const float* iw = (const float*)d_in[1];
    const float* th = (const float*)d_in[2];
    const float* ow = (const float*)d_in[3];
    float* out = (float*)d_out;
    const int batch = in_sizes[0] / NQ;
    hipLaunchKernelGGL(qnet_kernel, dim3(batch / 2), dim3(TPB), 0, stream,
                       x, iw, th, ow, out);
}

// Round 3
// 47.346 us; speedup vs baseline: 1.4790x; 1.4790x over previous
//
#include <hip/hip_runtime.h>

#define NQ 12
#define NL 5
#define TPB 256

// Storage layout: amplitude i (12-bit index) lives at byte address
//   A(i) = 16*(g ^ ((g>>3)&7)) + 8*(i&1),   g = i>>1   (granule-XOR swizzle)
// -> pass A is contiguous-b128 per thread with a 1-XOR lane spread (bank floor),
//    pass B is 1-XOR-vs-constant b64 (uniform banks),
//    pass C reads are static-offset b64 (zero addr VALU, uniform banks).
// CNOT ring (new[i] = old[f(i)], f(i)=i^(i>>1)^(bit0?0xC00:0)) is fused into the
// pass-C WRITE as a scatter to loc = f^-1(i) = D_t ^ CM[m]:
//   D_t = prefixXor(t) ^ (parity(t)<<11)  (once per thread)
//   CM[m] = (PX4(m)<<8) ^ (parity(m)?0x8FF:0)  (compile-time table)

__device__ __forceinline__ void gate_pair(float2 &a, float2 &c,
        const float2 u00, const float2 u01, const float2 u10, const float2 u11) {
    float2 n0, n1;
    n0.x = fmaf(u00.x, a.x, fmaf(-u00.y, a.y, fmaf(u01.x, c.x, -u01.y * c.y)));
    n0.y = fmaf(u00.x, a.y, fmaf( u00.y, a.x, fmaf(u01.x, c.y,  u01.y * c.x)));
    n1.x = fmaf(u10.x, a.x, fmaf(-u10.y, a.y, fmaf(u11.x, c.x, -u11.y * c.y)));
    n1.y = fmaf(u10.x, a.y, fmaf( u10.y, a.x, fmaf(u11.x, c.y,  u11.y * c.x)));
    a = n0; c = n1;
}

template <int K>
__device__ __forceinline__ void apply_gate(float2 (&v)[16], const float2* __restrict__ Uq) {
    const float2 u00 = Uq[0], u01 = Uq[1], u10 = Uq[2], u11 = Uq[3];
#pragma unroll
    for (int h = 0; h < 8; ++h) {
        const int m0 = ((h >> K) << (K + 1)) | (h & ((1 << K) - 1));
        gate_pair(v[m0], v[m0 | (1 << K)], u00, u01, u10, u11);
    }
}

extern "C" __global__ void __launch_bounds__(TPB)
qnet_kernel(const float* __restrict__ x, const float* __restrict__ iw,
            const float* __restrict__ th, const float* __restrict__ ow,
            float* __restrict__ out) {
    __shared__ float2 st[4096];          // 32 KB state, swizzled layout
    __shared__ float2 U[NL][NQ][4];      // gate matrices
    __shared__ float wz[4][4];
    char* stb = (char*)st;

    const int b = blockIdx.x;
    const int tid = threadIdx.x;

    // --- precompute all 60 gate matrices U = M(b,c) @ Rx(a) ---
    if (tid < NL * NQ) {
        const int l = tid / NQ, q = tid % NQ;
        const float xv = tanhf(x[b * NQ + q]);
        const float a = iw[l * NQ + q] * xv;
        const float bt = th[(l * NQ + q) * 2 + 0];
        const float ct = th[(l * NQ + q) * 2 + 1];
        float sa, ca; sincosf(0.5f * a, &sa, &ca);
        float sb, cb; sincosf(0.5f * bt, &sb, &cb);
        float sc, cc; sincosf(0.5f * ct, &sc, &cc);
        const float M00r = cc * cb, M00i = -sc * cb;
        const float M01r = -cc * sb, M01i = sc * sb;
        const float M10r = cc * sb, M10i = sc * sb;
        const float M11r = cc * cb, M11i = sc * cb;
        U[l][q][0] = make_float2(fmaf(M00r, ca,  sa * M01i), fmaf(M00i, ca, -sa * M01r));
        U[l][q][1] = make_float2(fmaf(ca, M01r,  sa * M00i), fmaf(ca, M01i, -sa * M00r));
        U[l][q][2] = make_float2(fmaf(M10r, ca,  sa * M11i), fmaf(M10i, ca, -sa * M11r));
        U[l][q][3] = make_float2(fmaf(ca, M11r,  sa * M10i), fmaf(ca, M11i, -sa * M10r));
    }

    // --- addressing constants (all cheap, once) ---
    const int baseA = (tid << 7) | ((tid & 7) << 4);                  // pass A: ^ (c<<4)
    const int baseB = ((tid >> 4) << 11) | ((tid & 15) << 3);         // pass B: ^ ((m<<7)|((m&7)<<4))
    const int baseC = (((tid >> 1) ^ ((tid >> 4) & 7)) << 4) | ((tid & 1) << 3); // pass C: + (m<<11)
    int pu = tid; pu ^= pu >> 1; pu ^= pu >> 2; pu ^= pu >> 4;        // prefix-xor from top (8-bit)
    const int Dt = pu ^ ((pu & 1) << 11);                             // f^-1 thread part
    constexpr int CM[16] = {0x000,0x9FF,0xBFF,0x200,0xFFF,0x600,0x400,0xDFF,
                            0x7FF,0xE00,0xC00,0x5FF,0x800,0x1FF,0x3FF,0xA00};

    __syncthreads();   // U visible

    float2 v[16];
    for (int l = 0; l < NL; ++l) {
        // --- pass A: amp bits 0-3 (qubits 11..8) ---
        if (l == 0) {
#pragma unroll
            for (int r = 0; r < 16; ++r) v[r] = make_float2(0.f, 0.f);
            if (tid == 0) v[0].x = 1.f;     // |0...0>
        } else {
#pragma unroll
            for (int c = 0; c < 8; ++c) {
                const float4 f = *(const float4*)(stb + (baseA ^ (c << 4)));
                v[2 * c]     = make_float2(f.x, f.y);
                v[2 * c + 1] = make_float2(f.z, f.w);
            }
        }
        apply_gate<0>(v, U[l][11]);
        apply_gate<1>(v, U[l][10]);
        apply_gate<2>(v, U[l][9]);
        apply_gate<3>(v, U[l][8]);
#pragma unroll
        for (int c = 0; c < 8; ++c) {
            *(float4*)(stb + (baseA ^ (c << 4))) =
                make_float4(v[2 * c].x, v[2 * c].y, v[2 * c + 1].x, v[2 * c + 1].y);
        }
        __syncthreads();

        // --- pass B: amp bits 4-7 (qubits 7..4); read/write same addrs ---
#pragma unroll
        for (int m = 0; m < 16; ++m)
            v[m] = *(const float2*)(stb + (baseB ^ ((m << 7) | ((m & 7) << 4))));
        apply_gate<0>(v, U[l][7]);
        apply_gate<1>(v, U[l][6]);
        apply_gate<2>(v, U[l][5]);
        apply_gate<3>(v, U[l][4]);
#pragma unroll
        for (int m = 0; m < 16; ++m)
            *(float2*)(stb + (baseB ^ ((m << 7) | ((m & 7) << 4)))) = v[m];
        __syncthreads();

        // --- pass C: amp bits 8-11 (qubits 3..0); static-offset reads ---
#pragma unroll
        for (int m = 0; m < 16; ++m)
            v[m] = *(const float2*)(stb + baseC + (m << 11));
        apply_gate<0>(v, U[l][3]);
        apply_gate<1>(v, U[l][2]);
        apply_gate<2>(v, U[l][1]);
        apply_gate<3>(v, U[l][0]);
        __syncthreads();   // all reads done before anyone scatters
        // scatter-write with fused CNOT-ring permutation: store amp i at f^-1(i)
#pragma unroll
        for (int m = 0; m < 16; ++m) {
            const int loc = Dt ^ CM[m];
            const int gl = loc >> 1;
            const int a = ((gl ^ ((gl >> 3) & 7)) << 4) | ((loc & 1) << 3);
            *(float2*)(stb + a) = v[m];
        }
        __syncthreads();
    }

    // --- measurement: state already CNOT-permuted; read own chunk (b128) ---
    float ps = 0.f;
#pragma unroll
    for (int c = 0; c < 8; ++c) {
        const float4 f = *(const float4*)(stb + (baseA ^ (c << 4)));
        ps = fmaf(f.x, f.x, fmaf(f.y, f.y, fmaf(f.z, f.z, fmaf(f.w, f.w, ps))));
    }
    // Z on qubits 0..3 = amp bits 11..8 = tid bits 7..4 (constant per thread)
    float s0 = (tid & 128) ? -ps : ps;
    float s1 = (tid & 64) ? -ps : ps;
    float s2 = (tid & 32) ? -ps : ps;
    float s3 = (tid & 16) ? -ps : ps;
#pragma unroll
    for (int off = 32; off > 0; off >>= 1) {
        s0 += __shfl_xor(s0, off);
        s1 += __shfl_xor(s1, off);
        s2 += __shfl_xor(s2, off);
        s3 += __shfl_xor(s3, off);
    }
    const int wave = tid >> 6;
    if ((tid & 63) == 0) {
        wz[wave][0] = s0; wz[wave][1] = s1; wz[wave][2] = s2; wz[wave][3] = s3;
    }
    __syncthreads();
    if (tid < 4) {
        const float z = wz[0][tid] + wz[1][tid] + wz[2][tid] + wz[3][tid];
        out[b * 4 + tid] = ow[tid] * z;
    }
}

extern "C" void kernel_launch(void* const* d_in, const int* in_sizes, int n_in,
                              void* d_out, int out_size, void* d_ws, size_t ws_size,
                              hipStream_t stream) {
    const float* x  = (const float*)d_in[0];
    const float* iw = (const float*)d_in[1];
    const float* th = (const float*)d_in[2];
    const float* ow = (const float*)d_in[3];
    float* out = (float*)d_out;
    const int batch = in_sizes[0] / NQ;
    hipLaunchKernelGGL(qnet_kernel, dim3(batch), dim3(TPB), 0, stream,
                       x, iw, th, ow, out);
}